// Round 11
// baseline (111.016 us; speedup 1.0000x reference)
//
#include <hip/hip_runtime.h>
#include <stdint.h>

#define HW 512
#define WPR 8                    // uint64 words per row (512/64)
#define IMG_WORDS (HW * WPR)     // 4096 words per image
#define NIMG 8
#define PIX_PER_IMG (HW * HW)
#define TOTAL_PIX (NIMG * PIX_PER_IMG)  // 2097152
#define MASK_WORDS (TOTAL_PIX / 64)     // 32768 words per mask set

#define NTASK 16                 // 8 gt + 8 pr images
#define NSTRIP 16
#define SROWS 32                 // owned rows per strip
#define GW 16                    // ghost halo width (rows per side)
#define BROWS 64                 // rows held per block
#define RSTRIDE 9                // row-major LDS stride (odd -> bank spread)
#define CS 16                    // substeps per chunk (= 8 iterations)
#define MAXCHUNK 38              // 304 iterations cap

#define CONV_U32 (NTASK * 64)                 // 1024: conv[task][chunk]
// halo: [task][iface(15)][dir(2)][parity(2)][16 rows * 8 words]
#define HALO_U64 (NTASK * 15 * 2 * 2 * 128)   // 122880

#define NBCE (TOTAL_PIX / 2048)               // 1024 bce blocks (8 px/thread)

// ---------------------------------------------------------------------------
// Init: zero the conv region (d_ws is poisoned 0xAA before every call).
// ---------------------------------------------------------------------------
__global__ __launch_bounds__(256) void init_kernel(uint32_t* __restrict__ conv) {
#pragma unroll
    for (int k = 0; k < 4; ++k) conv[threadIdx.x + k * 256] = 0u;
}

// ---------------------------------------------------------------------------
// Zhang-Suen bitwise compute, one word. Uw/Cw/Dw[1] = own column; [0]/[2]
// are W/E neighbor words. Bit i = pixel x = w*64+i; east = bit i+1.
// ---------------------------------------------------------------------------
__device__ __forceinline__ uint64_t zs1(int step, const uint64_t (&Uw)[3],
                                        const uint64_t (&Cw)[3],
                                        const uint64_t (&Dw)[3],
                                        uint64_t& NEW) {
    uint64_t P2 = Uw[1];                            // N
    uint64_t P6 = Dw[1];                            // S
    uint64_t P4 = (Cw[1] >> 1) | (Cw[2] << 63);     // E
    uint64_t P8 = (Cw[1] << 1) | (Cw[0] >> 63);     // W
    uint64_t P3 = (Uw[1] >> 1) | (Uw[2] << 63);     // NE
    uint64_t P9 = (Uw[1] << 1) | (Uw[0] >> 63);     // NW
    uint64_t P5 = (Dw[1] >> 1) | (Dw[2] << 63);     // SE
    uint64_t P7 = (Dw[1] << 1) | (Dw[0] >> 63);     // SW

    // B = popcount of 8 neighbors, bit-sliced CSA
    uint64_t s1 = P2 ^ P3, sum1 = s1 ^ P4, car1 = (P2 & P3) | (P4 & s1);
    uint64_t s2 = P5 ^ P6, sum2 = s2 ^ P7, car2 = (P5 & P6) | (P7 & s2);
    uint64_t s3 = sum1 ^ sum2, sum3 = s3 ^ P8, car3 = (sum1 & sum2) | (P8 & s3);
    uint64_t b0 = sum3 ^ P9, car4 = sum3 & P9;
    uint64_t s5 = car1 ^ car2, sum5 = s5 ^ car3, car5 = (car1 & car2) | (car3 & s5);
    uint64_t b1 = sum5 ^ car4, car6 = sum5 & car4;
    uint64_t b2 = car5 ^ car6, b3 = car5 & car6;
    uint64_t ge2 = b1 | b2 | b3;
    uint64_t le6 = ~(b3 | (b0 & b1 & b2));
    uint64_t condB = ge2 & le6;

    // A == 1: exactly one 0->1 transition around the ring
    uint64_t t0 = ~P2 & P3, t1 = ~P3 & P4, t2 = ~P4 & P5, t3 = ~P5 & P6;
    uint64_t t4 = ~P6 & P7, t5 = ~P7 & P8, t6 = ~P8 & P9, t7 = ~P9 & P2;
    uint64_t a01 = t0 | t1, a23 = t2 | t3, a45 = t4 | t5, a67 = t6 | t7;
    uint64_t m2 = (t0 & t1) | (t2 & t3) | (t4 & t5) | (t6 & t7);
    uint64_t a0123 = a01 | a23, a4567 = a45 | a67;
    m2 |= (a01 & a23) | (a45 & a67);
    m2 |= a0123 & a4567;
    uint64_t condA = (a0123 | a4567) & ~m2;

    uint64_t c1, c2;
    if (step == 0) {
        uint64_t q = P4 & P6;
        c1 = ~(q & P2);
        c2 = ~(q & P8);
    } else {
        uint64_t q = P2 & P8;
        c1 = ~(q & P4);
        c2 = ~(q & P6);
    }
    uint64_t rem = Cw[1] & condB & condA & c1 & c2;
    NEW = Cw[1] & ~rem;
    return rem;
}

// ---------------------------------------------------------------------------
// Ghost-zone skeletonize with fused binarization. Grid: 256 blocks x 512 thr
// (8 waves/CU). task = bid & 15, strip = bid >> 4. Thread owns ONE word
// (rl = tid>>3 in [0,64), wq = tid&7); LDS ping-pong [2][row][word].
// Binarize: each wave ballots 64 words straight from the float input.
// Chunk/sync structure identical to the round-6-verified design: CS=16
// barrier-only substeps on a GW=16 ghost zone (owned rows [16,48) stay exact;
// vote rows read only exact rows at substeps 14/15), then one global sync
// per chunk (publish parity halo slots -> release-add conv[task][chunk] ->
// spin all 16 strips -> uniform stop-or-consume). Parity slots overwrite-safe
// (conv barrier bounds skew < 2 chunks).
// ---------------------------------------------------------------------------
__global__ __launch_bounds__(512) void skel_kernel(const float* __restrict__ pred,
                                                   const float* __restrict__ target,
                                                   uint64_t* __restrict__ sk,
                                                   uint64_t* __restrict__ halo,
                                                   uint32_t* __restrict__ conv) {
    __shared__ uint64_t sbuf[2][BROWS * RSTRIDE];   // 9.2 KiB
    __shared__ int s_any8[8];
    __shared__ int s_dec;
    const int tid = threadIdx.x;
    const int task = blockIdx.x & (NTASK - 1);
    const int strip = blockIdx.x >> 4;
    const int rl = tid >> 3;            // 0..63 local row
    const int wq = tid & 7;             // owned word
    const int lane = tid & 63;
    const int wave = tid >> 6;
    const int gr0 = strip * SROWS - GW; // global row of rl=0
    const float* srcf = (task < 8 ? target : pred) + (size_t)(task & 7) * PIX_PER_IMG;
    uint64_t* dst = sk + (size_t)task * IMG_WORDS;

    // -- fused binarize: wave v ballots words k = v*64 + m (64 iters) --
    for (int m = 0; m < 64; ++m) {
        int k = wave * 64 + m;
        int r = k >> 3, w = k & 7;
        int gr = gr0 + r;
        float f = (gr >= 0 && gr < HW) ? srcf[gr * HW + w * 64 + lane] : 0.0f;
        uint64_t bits = __ballot(f > 0.5f);       // FILTER_P == 0.5 == gt thr
        if (lane == 0) sbuf[0][r * RSTRIDE + w] = bits;
    }
    __syncthreads();
    uint64_t C = sbuf[0][rl * RSTRIDE + wq];

    int cb = 0;
    const bool owned = (rl >= GW) && (rl < GW + SROWS);
    for (int chunk = 0; chunk < MAXCHUNK; ++chunk) {
        uint32_t tailch = 0;
        for (int ss = 0; ss < CS; ++ss) {
            const uint64_t* cur = sbuf[cb];
            uint64_t* nxt = sbuf[cb ^ 1];
            uint64_t Uw[3], Cw[3], Dw[3], NEW;
#pragma unroll
            for (int j = 0; j < 3; ++j) {
                int gw = wq - 1 + j;
                bool v = (gw >= 0) && (gw < 8);
                Uw[j] = (v && rl > 0)          ? cur[(rl - 1) * RSTRIDE + gw] : 0ull;
                Dw[j] = (v && rl < BROWS - 1)  ? cur[(rl + 1) * RSTRIDE + gw] : 0ull;
            }
            Cw[0] = (wq > 0) ? cur[rl * RSTRIDE + wq - 1] : 0ull;
            Cw[2] = (wq < 7) ? cur[rl * RSTRIDE + wq + 1] : 0ull;
            Cw[1] = C;
            uint64_t ch = zs1(ss & 1, Uw, Cw, Dw, NEW);
            if (ss >= CS - 2 && owned && ch) tailch = 1;   // last full iteration
            nxt[rl * RSTRIDE + wq] = NEW;
            C = NEW;
            cb ^= 1;
            __syncthreads();
        }

        const int par = chunk & 1;
        // -- publish owned boundary rows (from regs) --
        if (strip > 0 && rl >= GW && rl < 2 * GW) {          // bottom 16 owned
            uint64_t* hp = halo + ((((size_t)task * 15 + (strip - 1)) * 2 + 0) * 2 + par) * 128
                                + (rl - GW) * 8 + wq;
            __hip_atomic_store(hp, C, __ATOMIC_RELAXED, __HIP_MEMORY_SCOPE_AGENT);
            asm volatile("s_waitcnt vmcnt(0)" ::: "memory");
        }
        if (strip < NSTRIP - 1 && rl >= 32 && rl < 48) {     // top 16 owned
            uint64_t* hp = halo + ((((size_t)task * 15 + strip) * 2 + 1) * 2 + par) * 128
                                + (rl - 32) * 8 + wq;
            __hip_atomic_store(hp, C, __ATOMIC_RELAXED, __HIP_MEMORY_SCOPE_AGENT);
            asm volatile("s_waitcnt vmcnt(0)" ::: "memory");
        }
        int wa = __any((int)tailch);
        if (lane == 0) s_any8[wave] = wa;
        __syncthreads();   // publish stores drained by all waves before the add
        if (tid == 0) {
            int any = s_any8[0] | s_any8[1] | s_any8[2] | s_any8[3]
                    | s_any8[4] | s_any8[5] | s_any8[6] | s_any8[7];
            uint32_t add = 256u + (any ? 1u : 0u);
            uint32_t* cp = &conv[task * 64 + chunk];
            uint32_t v = __hip_atomic_fetch_add(cp, add, __ATOMIC_RELEASE,
                                                __HIP_MEMORY_SCOPE_AGENT) + add;
            while ((v >> 8) < (uint32_t)NSTRIP)
                v = __hip_atomic_load(cp, __ATOMIC_ACQUIRE, __HIP_MEMORY_SCOPE_AGENT);
            s_dec = ((v & 0xffu) != 0u) ? 1 : 0;   // 1 = some strip still changing
        }
        __syncthreads();
        if (!s_dec) break;     // uniform across all strips of this task

        // -- consume neighbor halos into regs + current buffer --
        if (strip > 0 && rl < GW) {                          // lower halo
            const uint64_t* hp = halo + ((((size_t)task * 15 + (strip - 1)) * 2 + 1) * 2 + par) * 128
                                      + rl * 8 + wq;
            C = __hip_atomic_load(hp, __ATOMIC_RELAXED, __HIP_MEMORY_SCOPE_AGENT);
            sbuf[cb][rl * RSTRIDE + wq] = C;
        }
        if (strip < NSTRIP - 1 && rl >= 48) {                // upper halo
            const uint64_t* hp = halo + ((((size_t)task * 15 + strip) * 2 + 0) * 2 + par) * 128
                                      + (rl - 48) * 8 + wq;
            C = __hip_atomic_load(hp, __ATOMIC_RELAXED, __HIP_MEMORY_SCOPE_AGENT);
            sbuf[cb][rl * RSTRIDE + wq] = C;
        }
        __syncthreads();
    }

    if (owned) {
        int gr = gr0 + rl;
        dst[gr * WPR + wq] = C;
    }
}

// ---------------------------------------------------------------------------
// BCE (branchless, float4). Binary masks recomputed from the floats already
// loaded (gt_bin = t>0.5, pr_bin = p>0.5) -> no bin-mask arrays needed.
// Contention-free epilogue: unique partial slot per block.
// ---------------------------------------------------------------------------
__global__ __launch_bounds__(256) void bce_kernel(
        const float4* __restrict__ pred4, const float4* __restrict__ tgt4,
        const uint64_t* __restrict__ gt_sk, const uint64_t* __restrict__ pr_sk,
        float* __restrict__ psum, int* __restrict__ pcnt) {
    int tg = blockIdx.x * 256 + threadIdx.x;     // 8 px per thread
    int w = tg >> 3;
    int sh = (tg & 7) * 8;
    uint32_t gbits = (uint32_t)(gt_sk[w] >> sh) & 0xffu;
    uint32_t pbits = (uint32_t)(pr_sk[w] >> sh) & 0xffu;
    float4 pa = pred4[2 * tg], pb = pred4[2 * tg + 1];
    float4 ta = tgt4[2 * tg], tb = tgt4[2 * tg + 1];
    float p[8] = {pa.x, pa.y, pa.z, pa.w, pb.x, pb.y, pb.z, pb.w};
    float t[8] = {ta.x, ta.y, ta.z, ta.w, tb.x, tb.y, tb.z, tb.w};
    float lsum = 0.0f;
    int lcnt = 0;
#pragma unroll
    for (int j = 0; j < 8; ++j) {
        float lp = fmaxf(logf(p[j]), -100.0f);
        float l1 = fmaxf(log1pf(-p[j]), -100.0f);
        float b = -(t[j] * lp + (1.0f - t[j]) * l1);
        uint32_t prb = (p[j] > 0.5f) ? 1u : 0u;          // pr_bin
        uint32_t gtb = (t[j] > 0.5f) ? 1u : 0u;          // gt_bin
        uint32_t m = (((gbits >> j) & 1u) & (prb ^ 1u))  // gt_sk & ~pr_bin
                   | (((pbits >> j) & 1u) & (gtb ^ 1u)); // pr_sk & ~gt_bin
        lsum = fmaf((float)m, b, lsum);
        lcnt += (int)m;
    }
#pragma unroll
    for (int off = 32; off > 0; off >>= 1) {
        lsum += __shfl_down(lsum, off, 64);
        lcnt += __shfl_down(lcnt, off, 64);
    }
    __shared__ float sred[4];
    __shared__ int cred[4];
    int wave = threadIdx.x >> 6, lane = threadIdx.x & 63;
    if (lane == 0) { sred[wave] = lsum; cred[wave] = lcnt; }
    __syncthreads();
    if (threadIdx.x == 0) {
        psum[blockIdx.x] = sred[0] + sred[1] + sred[2] + sred[3];
        pcnt[blockIdx.x] = cred[0] + cred[1] + cred[2] + cred[3];
    }
}

// ---------------------------------------------------------------------------
// Final: reduce 1024 partials (128 blocks per image -> 2 waves per image).
// ---------------------------------------------------------------------------
__global__ __launch_bounds__(1024) void final_kernel(const float* __restrict__ psum,
                                                     const int* __restrict__ pcnt,
                                                     float* __restrict__ out) {
    int t = threadIdx.x;
    float s = psum[t];
    int c = pcnt[t];
#pragma unroll
    for (int off = 32; off > 0; off >>= 1) {
        s += __shfl_down(s, off, 64);
        c += __shfl_down(c, off, 64);
    }
    __shared__ float ss[16];
    __shared__ int sc[16];
    int w = t >> 6;
    if ((t & 63) == 0) { ss[w] = s; sc[w] = c; }
    __syncthreads();
    if (t == 0) {
        float tot = 0.0f;
#pragma unroll
        for (int i = 0; i < NIMG; ++i) {          // img i = waves 2i, 2i+1
            float sv = ss[2 * i] + ss[2 * i + 1];
            int cv = sc[2 * i] + sc[2 * i + 1];
            tot += (cv > 0) ? sv / (float)cv : 0.0f;
        }
        out[0] = tot * (1.0f / NIMG);
    }
}

// ---------------------------------------------------------------------------
extern "C" void kernel_launch(void* const* d_in, const int* in_sizes, int n_in,
                              void* d_out, int out_size, void* d_ws, size_t ws_size,
                              hipStream_t stream) {
    const float* pred = (const float*)d_in[0];
    const float* target = (const float*)d_in[1];
    uint64_t* ws = (uint64_t*)d_ws;
    uint64_t* sk    = ws;                        // 16 tasks x 4096 words
    uint64_t* gt_sk = sk;                        // tasks 0..7
    uint64_t* pr_sk = sk + MASK_WORDS;           // tasks 8..15
    uint64_t* halo  = ws + 2 * MASK_WORDS;       // HALO_U64
    uint32_t* conv  = (uint32_t*)(halo + HALO_U64);
    float* psum     = (float*)(conv + CONV_U32); // 1024 floats
    int* pcnt       = (int*)(psum + NBCE);       // 1024 ints

    init_kernel<<<1, 256, 0, stream>>>(conv);
    skel_kernel<<<NTASK * NSTRIP, 512, 0, stream>>>(pred, target, sk, halo, conv);
    bce_kernel<<<NBCE, 256, 0, stream>>>((const float4*)pred, (const float4*)target,
                                         gt_sk, pr_sk, psum, pcnt);
    final_kernel<<<1, 1024, 0, stream>>>(psum, pcnt, (float*)d_out);
}

// Round 12
// 94.007 us; speedup vs baseline: 1.1809x; 1.1809x over previous
//
#include <hip/hip_runtime.h>
#include <stdint.h>

#define HW 512
#define WPR 8                    // uint64 words per row (512/64)
#define IMG_WORDS (HW * WPR)     // 4096 words per image
#define NIMG 8
#define PIX_PER_IMG (HW * HW)
#define TOTAL_PIX (NIMG * PIX_PER_IMG)  // 2097152
#define MASK_WORDS (TOTAL_PIX / 64)     // 32768 words per mask set

#define NTASK 16                 // 8 gt + 8 pr images
#define NSTRIP 16
#define SROWS 32                 // owned rows per strip
#define GW 16                    // ghost halo width (rows per side)
#define BROWS 64                 // SROWS + 2*GW rows held per block
#define LSTRIDE 65               // padded LDS row stride (col-major, verified r6-r10)
#define CS 16                    // substeps per chunk (= 8 iterations)
#define MAXCHUNK 38              // 304 iterations cap

// ctrl region (uint32): conv[task][chunk] only
#define CONV_U32 (NTASK * 64)                 // 1024
// halo: [task][iface(15)][dir(2)][parity(2)][16 rows * 8 words]
#define HALO_U64 (NTASK * 15 * 2 * 2 * 128)   // 122880

#define NBCE (TOTAL_PIX / 2048)               // 1024 bce blocks (8 px/thread)

// ---------------------------------------------------------------------------
// Pack: binarize into bit masks at device width; zero the conv region.
// ---------------------------------------------------------------------------
__global__ void pack_kernel(const float* __restrict__ pred,
                            const float* __restrict__ target,
                            uint64_t* __restrict__ gt_bin,
                            uint64_t* __restrict__ pr_bin,
                            uint32_t* __restrict__ conv) {
    int idx = blockIdx.x * 256 + threadIdx.x;
    if (blockIdx.x < 4) {
        int z = blockIdx.x * 256 + threadIdx.x;
        conv[z] = 0u;                 // z < 1024 == CONV_U32
    }
    float p = pred[idx];
    float t = target[idx];
    uint64_t bp = __ballot(p > 0.5f);   // FILTER_P
    uint64_t bt = __ballot(t > 0.5f);
    if ((threadIdx.x & 63) == 0) {
        int w = idx >> 6;
        pr_bin[w] = bp;
        gt_bin[w] = bt;
    }
}

// ---------------------------------------------------------------------------
// Zhang-Suen bitwise compute on a 2-word window. Arrays index j: global word
// wb-1+j; own words are j=1..2.
// ---------------------------------------------------------------------------
__device__ __forceinline__ uint64_t zs_win2(int step, const uint64_t (&Uw)[4],
                                            const uint64_t (&Cw)[4],
                                            const uint64_t (&Dw)[4],
                                            uint64_t (&NEW)[2]) {
    uint64_t changed = 0;
#pragma unroll
    for (int j = 1; j <= 2; ++j) {
        uint64_t P2 = Uw[j];                              // N
        uint64_t P6 = Dw[j];                              // S
        uint64_t P4 = (Cw[j] >> 1) | (Cw[j + 1] << 63);   // E
        uint64_t P8 = (Cw[j] << 1) | (Cw[j - 1] >> 63);   // W
        uint64_t P3 = (Uw[j] >> 1) | (Uw[j + 1] << 63);   // NE
        uint64_t P9 = (Uw[j] << 1) | (Uw[j - 1] >> 63);   // NW
        uint64_t P5 = (Dw[j] >> 1) | (Dw[j + 1] << 63);   // SE
        uint64_t P7 = (Dw[j] << 1) | (Dw[j - 1] >> 63);   // SW

        // B = popcount of 8 neighbors, bit-sliced CSA
        uint64_t s1 = P2 ^ P3, sum1 = s1 ^ P4, car1 = (P2 & P3) | (P4 & s1);
        uint64_t s2 = P5 ^ P6, sum2 = s2 ^ P7, car2 = (P5 & P6) | (P7 & s2);
        uint64_t s3 = sum1 ^ sum2, sum3 = s3 ^ P8, car3 = (sum1 & sum2) | (P8 & s3);
        uint64_t b0 = sum3 ^ P9, car4 = sum3 & P9;
        uint64_t s5 = car1 ^ car2, sum5 = s5 ^ car3, car5 = (car1 & car2) | (car3 & s5);
        uint64_t b1 = sum5 ^ car4, car6 = sum5 & car4;
        uint64_t b2 = car5 ^ car6, b3 = car5 & car6;
        uint64_t ge2 = b1 | b2 | b3;
        uint64_t le6 = ~(b3 | (b0 & b1 & b2));
        uint64_t condB = ge2 & le6;

        // A == 1: exactly one 0->1 transition around the ring
        uint64_t t0 = ~P2 & P3, t1 = ~P3 & P4, t2 = ~P4 & P5, t3 = ~P5 & P6;
        uint64_t t4 = ~P6 & P7, t5 = ~P7 & P8, t6 = ~P8 & P9, t7 = ~P9 & P2;
        uint64_t a01 = t0 | t1, a23 = t2 | t3, a45 = t4 | t5, a67 = t6 | t7;
        uint64_t m2 = (t0 & t1) | (t2 & t3) | (t4 & t5) | (t6 & t7);
        uint64_t a0123 = a01 | a23, a4567 = a45 | a67;
        m2 |= (a01 & a23) | (a45 & a67);
        m2 |= a0123 & a4567;
        uint64_t condA = (a0123 | a4567) & ~m2;

        uint64_t c1, c2;
        if (step == 0) {
            uint64_t q = P4 & P6;
            c1 = ~(q & P2);
            c2 = ~(q & P8);
        } else {
            uint64_t q = P2 & P8;
            c1 = ~(q & P4);
            c2 = ~(q & P6);
        }
        uint64_t rem = Cw[j] & condB & condA & c1 & c2;
        NEW[j - 1] = Cw[j] & ~rem;
        changed |= rem;
    }
    return changed;
}

// ---------------------------------------------------------------------------
// Ghost-zone skeletonize — EXACT round-10 version (measured ~28 us in budget;
// r11's 512-thr fused-binarize variant regressed to 48-52 us, reverted).
// See round-6 header for the correctness argument.
// ---------------------------------------------------------------------------
__global__ __launch_bounds__(256) void skel_kernel(const uint64_t* __restrict__ bin,
                                                   uint64_t* __restrict__ sk,
                                                   uint64_t* __restrict__ halo,
                                                   uint32_t* __restrict__ conv) {
    __shared__ uint64_t sbuf[2][WPR * LSTRIDE];   // 8.3 KiB
    __shared__ int s_any4[4];
    __shared__ int s_dec;
    const int tid = threadIdx.x;
    const int task = blockIdx.x & (NTASK - 1);
    const int strip = blockIdx.x >> 4;
    const int rl = tid >> 2;            // 0..63 local row
    const int wb = (tid & 3) * 2;       // first owned word
    const int gr0 = strip * SROWS - GW; // global row of rl=0
    const uint64_t* src = bin + (size_t)task * IMG_WORDS;
    uint64_t* dst = sk + (size_t)task * IMG_WORDS;

    uint64_t C[2];
    {
        int gr = gr0 + rl;
        bool in = (gr >= 0) && (gr < HW);
        C[0] = in ? src[gr * WPR + wb] : 0ull;
        C[1] = in ? src[gr * WPR + wb + 1] : 0ull;
        sbuf[0][wb * LSTRIDE + rl] = C[0];
        sbuf[0][(wb + 1) * LSTRIDE + rl] = C[1];
    }
    __syncthreads();

    int cb = 0;
    const bool owned = (rl >= GW) && (rl < GW + SROWS);
    for (int chunk = 0; chunk < MAXCHUNK; ++chunk) {
        uint32_t tailch = 0;
        for (int ss = 0; ss < CS; ++ss) {
            const uint64_t* cur = sbuf[cb];
            uint64_t* nxt = sbuf[cb ^ 1];
            uint64_t Uw[4], Dw[4], Cw[4], NEW[2];
#pragma unroll
            for (int j = 0; j < 4; ++j) {
                int gw = wb - 1 + j;
                bool v = (gw >= 0) && (gw < 8);
                Uw[j] = (v && rl > 0)          ? cur[gw * LSTRIDE + rl - 1] : 0ull;
                Dw[j] = (v && rl < BROWS - 1)  ? cur[gw * LSTRIDE + rl + 1] : 0ull;
            }
            Cw[0] = (wb > 0) ? cur[(wb - 1) * LSTRIDE + rl] : 0ull;
            Cw[3] = (wb < 6) ? cur[(wb + 2) * LSTRIDE + rl] : 0ull;
            Cw[1] = C[0];
            Cw[2] = C[1];
            uint64_t ch = zs_win2(ss & 1, Uw, Cw, Dw, NEW);
            if (ss >= CS - 2 && owned && ch) tailch = 1;   // last full iteration
            nxt[wb * LSTRIDE + rl] = NEW[0];
            nxt[(wb + 1) * LSTRIDE + rl] = NEW[1];
            C[0] = NEW[0];
            C[1] = NEW[1];
            cb ^= 1;
            __syncthreads();
        }

        const int par = chunk & 1;
        // -- publish owned boundary rows (from regs; device-coherent stores) --
        if (strip > 0 && rl >= GW && rl < 2 * GW) {          // bottom 16 owned
            uint64_t* hp = halo + ((((size_t)task * 15 + (strip - 1)) * 2 + 0) * 2 + par) * 128
                                + (rl - GW) * 8 + wb;
            __hip_atomic_store(hp, C[0], __ATOMIC_RELAXED, __HIP_MEMORY_SCOPE_AGENT);
            __hip_atomic_store(hp + 1, C[1], __ATOMIC_RELAXED, __HIP_MEMORY_SCOPE_AGENT);
            asm volatile("s_waitcnt vmcnt(0)" ::: "memory");
        }
        if (strip < NSTRIP - 1 && rl >= 32 && rl < 48) {     // top 16 owned
            uint64_t* hp = halo + ((((size_t)task * 15 + strip) * 2 + 1) * 2 + par) * 128
                                + (rl - 32) * 8 + wb;
            __hip_atomic_store(hp, C[0], __ATOMIC_RELAXED, __HIP_MEMORY_SCOPE_AGENT);
            __hip_atomic_store(hp + 1, C[1], __ATOMIC_RELAXED, __HIP_MEMORY_SCOPE_AGENT);
            asm volatile("s_waitcnt vmcnt(0)" ::: "memory");
        }
        int wa = __any((int)tailch);
        if ((tid & 63) == 0) s_any4[tid >> 6] = wa;
        __syncthreads();   // publish stores drained by all waves before the add
        if (tid == 0) {
            uint32_t add = 256u + ((s_any4[0] | s_any4[1] | s_any4[2] | s_any4[3]) ? 1u : 0u);
            uint32_t* cp = &conv[task * 64 + chunk];
            uint32_t v = __hip_atomic_fetch_add(cp, add, __ATOMIC_RELEASE,
                                                __HIP_MEMORY_SCOPE_AGENT) + add;
            while ((v >> 8) < (uint32_t)NSTRIP)
                v = __hip_atomic_load(cp, __ATOMIC_ACQUIRE, __HIP_MEMORY_SCOPE_AGENT);
            s_dec = ((v & 0xffu) != 0u) ? 1 : 0;   // 1 = some strip still changing
        }
        __syncthreads();
        if (!s_dec) break;     // uniform across all strips of this task

        // -- consume neighbor halos into regs + current buffer --
        if (strip > 0 && rl < GW) {                          // lower halo
            const uint64_t* hp = halo + ((((size_t)task * 15 + (strip - 1)) * 2 + 1) * 2 + par) * 128
                                      + rl * 8 + wb;
            C[0] = __hip_atomic_load(hp, __ATOMIC_RELAXED, __HIP_MEMORY_SCOPE_AGENT);
            C[1] = __hip_atomic_load(hp + 1, __ATOMIC_RELAXED, __HIP_MEMORY_SCOPE_AGENT);
            sbuf[cb][wb * LSTRIDE + rl] = C[0];
            sbuf[cb][(wb + 1) * LSTRIDE + rl] = C[1];
        }
        if (strip < NSTRIP - 1 && rl >= 48) {                // upper halo
            const uint64_t* hp = halo + ((((size_t)task * 15 + strip) * 2 + 0) * 2 + par) * 128
                                      + (rl - 48) * 8 + wb;
            C[0] = __hip_atomic_load(hp, __ATOMIC_RELAXED, __HIP_MEMORY_SCOPE_AGENT);
            C[1] = __hip_atomic_load(hp + 1, __ATOMIC_RELAXED, __HIP_MEMORY_SCOPE_AGENT);
            sbuf[cb][wb * LSTRIDE + rl] = C[0];
            sbuf[cb][(wb + 1) * LSTRIDE + rl] = C[1];
        }
        __syncthreads();
    }

    if (owned) {
        int gr = gr0 + rl;
        dst[gr * WPR + wb] = C[0];
        dst[gr * WPR + wb + 1] = C[1];
    }
}

// ---------------------------------------------------------------------------
// BCE (branchless, float4; r11 version). Binary masks recomputed from the
// floats already loaded -> no bin-mask array loads. Contention-free epilogue.
// ---------------------------------------------------------------------------
__global__ __launch_bounds__(256) void bce_kernel(
        const float4* __restrict__ pred4, const float4* __restrict__ tgt4,
        const uint64_t* __restrict__ gt_sk, const uint64_t* __restrict__ pr_sk,
        float* __restrict__ psum, int* __restrict__ pcnt) {
    int tg = blockIdx.x * 256 + threadIdx.x;     // 8 px per thread
    int w = tg >> 3;
    int sh = (tg & 7) * 8;
    uint32_t gbits = (uint32_t)(gt_sk[w] >> sh) & 0xffu;
    uint32_t pbits = (uint32_t)(pr_sk[w] >> sh) & 0xffu;
    float4 pa = pred4[2 * tg], pb = pred4[2 * tg + 1];
    float4 ta = tgt4[2 * tg], tb = tgt4[2 * tg + 1];
    float p[8] = {pa.x, pa.y, pa.z, pa.w, pb.x, pb.y, pb.z, pb.w};
    float t[8] = {ta.x, ta.y, ta.z, ta.w, tb.x, tb.y, tb.z, tb.w};
    float lsum = 0.0f;
    int lcnt = 0;
#pragma unroll
    for (int j = 0; j < 8; ++j) {
        float lp = fmaxf(logf(p[j]), -100.0f);
        float l1 = fmaxf(log1pf(-p[j]), -100.0f);
        float b = -(t[j] * lp + (1.0f - t[j]) * l1);
        uint32_t prb = (p[j] > 0.5f) ? 1u : 0u;          // pr_bin
        uint32_t gtb = (t[j] > 0.5f) ? 1u : 0u;          // gt_bin
        uint32_t m = (((gbits >> j) & 1u) & (prb ^ 1u))  // gt_sk & ~pr_bin
                   | (((pbits >> j) & 1u) & (gtb ^ 1u)); // pr_sk & ~gt_bin
        lsum = fmaf((float)m, b, lsum);
        lcnt += (int)m;
    }
#pragma unroll
    for (int off = 32; off > 0; off >>= 1) {
        lsum += __shfl_down(lsum, off, 64);
        lcnt += __shfl_down(lcnt, off, 64);
    }
    __shared__ float sred[4];
    __shared__ int cred[4];
    int wave = threadIdx.x >> 6, lane = threadIdx.x & 63;
    if (lane == 0) { sred[wave] = lsum; cred[wave] = lcnt; }
    __syncthreads();
    if (threadIdx.x == 0) {
        psum[blockIdx.x] = sred[0] + sred[1] + sred[2] + sred[3];
        pcnt[blockIdx.x] = cred[0] + cred[1] + cred[2] + cred[3];
    }
}

// ---------------------------------------------------------------------------
// Final: reduce 1024 partials (128 blocks per image -> 2 waves per image).
// ---------------------------------------------------------------------------
__global__ __launch_bounds__(1024) void final_kernel(const float* __restrict__ psum,
                                                     const int* __restrict__ pcnt,
                                                     float* __restrict__ out) {
    int t = threadIdx.x;
    float s = psum[t];
    int c = pcnt[t];
#pragma unroll
    for (int off = 32; off > 0; off >>= 1) {
        s += __shfl_down(s, off, 64);
        c += __shfl_down(c, off, 64);
    }
    __shared__ float ss[16];
    __shared__ int sc[16];
    int w = t >> 6;
    if ((t & 63) == 0) { ss[w] = s; sc[w] = c; }
    __syncthreads();
    if (t == 0) {
        float tot = 0.0f;
#pragma unroll
        for (int i = 0; i < NIMG; ++i) {          // img i = waves 2i, 2i+1
            float sv = ss[2 * i] + ss[2 * i + 1];
            int cv = sc[2 * i] + sc[2 * i + 1];
            tot += (cv > 0) ? sv / (float)cv : 0.0f;
        }
        out[0] = tot * (1.0f / NIMG);
    }
}

// ---------------------------------------------------------------------------
extern "C" void kernel_launch(void* const* d_in, const int* in_sizes, int n_in,
                              void* d_out, int out_size, void* d_ws, size_t ws_size,
                              hipStream_t stream) {
    const float* pred = (const float*)d_in[0];
    const float* target = (const float*)d_in[1];
    uint64_t* ws = (uint64_t*)d_ws;
    uint64_t* gt_bin = ws;                      // 32768 u64 (gt then pr = 16 tasks)
    uint64_t* pr_bin = ws + MASK_WORDS;
    uint64_t* gt_sk  = ws + 2 * MASK_WORDS;
    uint64_t* pr_sk  = ws + 3 * MASK_WORDS;
    uint64_t* halo   = ws + 4 * MASK_WORDS;     // HALO_U64
    uint32_t* conv   = (uint32_t*)(halo + HALO_U64);
    float* psum      = (float*)(conv + CONV_U32);       // 1024 floats
    int* pcnt        = (int*)(psum + NBCE);             // 1024 ints

    pack_kernel<<<TOTAL_PIX / 256, 256, 0, stream>>>(pred, target, gt_bin, pr_bin, conv);
    skel_kernel<<<NTASK * NSTRIP, 256, 0, stream>>>(gt_bin, gt_sk, halo, conv);
    bce_kernel<<<NBCE, 256, 0, stream>>>((const float4*)pred, (const float4*)target,
                                         gt_sk, pr_sk, psum, pcnt);
    final_kernel<<<1, 1024, 0, stream>>>(psum, pcnt, (float*)d_out);
}